// Round 5
// baseline (324.165 us; speedup 1.0000x reference)
//
#include <hip/hip_runtime.h>
#include <math.h>

#define DIM 480          // 128*1 + 64*3 + 32*5
#define ROWS 8           // rows per wave
#define BLOCK 64         // one wave per block: no __syncthreads anywhere
#define NLOADS 15        // ROWS*DIM*4B / 1024B  (15 x 1KB global_load_lds)

typedef float f4 __attribute__((ext_vector_type(4)));  // native vec: ok for nt-store

// scaling = silu(max(n,eps))/max(n,eps) == sigmoid(max(n,eps))
__device__ __forceinline__ float sig_of(float n) {
    n = fmaxf(n, 1e-8f);
    return __builtin_amdgcn_rcpf(1.0f + __expf(-n));
}

// Scale all groups of ROWS rows in-place in LDS.
// Bank analysis (32 banks, row stride 480 == 0 mod 32):
//   A: b128 unit-stride pattern (same as drain loop) -> conflict-free
//   B: stride 3, C: stride 5 (gcd=1 with 32) -> <=2-way aliasing (free, m136)
template <int R>
__device__ __forceinline__ void scale_groups(float* sbuf, int lane) {
    // region A: R*128 d=1 groups, vectorized b128 RMW (4 groups per lane-iter)
    #pragma unroll
    for (int k = 0; k < R / 2; ++k) {            // R*128/4 float4s / 64 lanes
        const int a4 = k * 64 + lane;            // [0, R*32)
        f4* p = (f4*)(sbuf + (a4 >> 5) * DIM) + (a4 & 31);
        f4 x = *p;
        x.x *= sig_of(fabsf(x.x));
        x.y *= sig_of(fabsf(x.y));
        x.z *= sig_of(fabsf(x.z));
        x.w *= sig_of(fabsf(x.w));
        *p = x;
    }
    // region B: R*64 d=3 groups
    #pragma unroll
    for (int k = 0; k < R; ++k) {
        const int b = k * 64 + lane;
        float* p = sbuf + (b >> 6) * DIM + 128 + 3 * (b & 63);
        const float x0 = p[0], x1 = p[1], x2 = p[2];
        const float s = sig_of(sqrtf(x0*x0 + x1*x1 + x2*x2));
        p[0] = x0 * s; p[1] = x1 * s; p[2] = x2 * s;
    }
    // region C: R*32 d=5 groups
    #pragma unroll
    for (int k = 0; k < R / 2; ++k) {
        const int c = k * 64 + lane;
        float* p = sbuf + (c >> 5) * DIM + 320 + 5 * (c & 31);
        const float x0 = p[0], x1 = p[1], x2 = p[2], x3 = p[3], x4 = p[4];
        const float s = sig_of(sqrtf(x0*x0 + x1*x1 + x2*x2 + x3*x3 + x4*x4));
        p[0] = x0*s; p[1] = x1*s; p[2] = x2*s; p[3] = x3*s; p[4] = x4*s;
    }
}

__device__ void scale_groups_rt(float* sbuf, int lane, int rows) {
    for (int a = lane; a < rows * 128; a += 64) {
        float* p = sbuf + (a >> 7) * DIM + (a & 127);
        const float x = *p;
        *p = x * sig_of(fabsf(x));
    }
    for (int b = lane; b < rows * 64; b += 64) {
        float* p = sbuf + (b >> 6) * DIM + 128 + 3 * (b & 63);
        const float x0 = p[0], x1 = p[1], x2 = p[2];
        const float s = sig_of(sqrtf(x0*x0 + x1*x1 + x2*x2));
        p[0] = x0 * s; p[1] = x1 * s; p[2] = x2 * s;
    }
    for (int c = lane; c < rows * 32; c += 64) {
        float* p = sbuf + (c >> 5) * DIM + 320 + 5 * (c & 31);
        const float x0 = p[0], x1 = p[1], x2 = p[2], x3 = p[3], x4 = p[4];
        const float s = sig_of(sqrtf(x0*x0 + x1*x1 + x2*x2 + x3*x3 + x4*x4));
        p[0] = x0*s; p[1] = x1*s; p[2] = x2*s; p[3] = x3*s; p[4] = x4*s;
    }
}

__global__ __launch_bounds__(BLOCK) void norm_act_kernel(
    const float* __restrict__ in, float* __restrict__ out, int n_rows)
{
    __shared__ __align__(16) float sbuf[ROWS * DIM];   // 15360 B -> 10 blocks/CU
    const int lane = threadIdx.x;
    const int row0 = blockIdx.x * ROWS;
    const int rows = min(ROWS, n_rows - row0);

    const float* gsrc = in  + (size_t)row0 * DIM;
    float*       gdst = out + (size_t)row0 * DIM;

    if (rows == ROWS) {
        // ---- stage: 15 x 1KB coalesced direct-to-LDS (no VGPR round-trip) ----
        #pragma unroll
        for (int k = 0; k < NLOADS; ++k) {
            const float* gp = gsrc + (size_t)(k * 64 + lane) * 4;  // per-lane 16B
            __builtin_amdgcn_global_load_lds(
                (const __attribute__((address_space(1))) void*)gp,
                (__attribute__((address_space(3))) void*)((char*)sbuf + k * 1024),
                16, 0, 0);
        }
        asm volatile("s_waitcnt vmcnt(0)" ::: "memory");  // wave-local; no barrier

        // ---- compute: in-place group scaling in LDS ----
        scale_groups<ROWS>(sbuf, lane);

        // ---- drain: ds_read_b128 -> NON-TEMPORAL global_store_dwordx4 ----
        // output stream is never re-read: nt skips L2/L3 allocation so cache
        // capacity + victim BW stay dedicated to the read stream.
        #pragma unroll
        for (int k = 0; k < NLOADS; ++k) {
            const int v = k * 64 + lane;
            __builtin_nontemporal_store(((const f4*)sbuf)[v], (f4*)gdst + v);
        }
    } else if (rows > 0) {
        // tail block (not hit for n_rows=100000): plain staging, runtime bounds
        for (int v = lane; v < rows * (DIM / 4); v += BLOCK)
            ((f4*)sbuf)[v] = ((const f4*)gsrc)[v];
        scale_groups_rt(sbuf, lane, rows);
        for (int v = lane; v < rows * (DIM / 4); v += BLOCK)
            __builtin_nontemporal_store(((const f4*)sbuf)[v], (f4*)gdst + v);
    }
}

extern "C" void kernel_launch(void* const* d_in, const int* in_sizes, int n_in,
                              void* d_out, int out_size, void* d_ws, size_t ws_size,
                              hipStream_t stream) {
    const float* in  = (const float*)d_in[0];
    float*       out = (float*)d_out;
    const int n_rows = in_sizes[0] / DIM;                  // 100000
    const int grid   = (n_rows + ROWS - 1) / ROWS;         // 12500 wave-blocks
    norm_act_kernel<<<grid, BLOCK, 0, stream>>>(in, out, n_rows);
}